// Round 2
// baseline (350.863 us; speedup 1.0000x reference)
//
#include <hip/hip_runtime.h>
#include <cstdint>

typedef unsigned short u16;
typedef short v8s __attribute__((ext_vector_type(8)));   // 8 bf16 (4 VGPRs) MFMA A/B frag
typedef float v4f __attribute__((ext_vector_type(4)));   // MFMA C/D frag
typedef u16 u16x8 __attribute__((ext_vector_type(8)));
typedef u16 u16x4 __attribute__((ext_vector_type(4)));

static constexpr int Bb = 8, Cc = 512, Ll = 2048, Hh = 8, Dh = 64;

__device__ __forceinline__ float bf2f(u16 u){
  unsigned x = ((unsigned)u) << 16; float f; __builtin_memcpy(&f, &x, 4); return f;
}
__device__ __forceinline__ u16 f2bf(float f){
  unsigned x; __builtin_memcpy(&x, &f, 4);
  x = (x + 0x7fffu + ((x >> 16) & 1u)) >> 16; return (u16)x;  // RNE
}

__device__ __forceinline__ void async_cp16(const u16* g, u16* l){
  __builtin_amdgcn_global_load_lds(
      (const __attribute__((address_space(1))) unsigned int*)g,
      (__attribute__((address_space(3))) unsigned int*)l, 16, 0, 0);
}

#if __has_builtin(__builtin_amdgcn_exp2f)
#define EXP2F(x) __builtin_amdgcn_exp2f(x)
#else
#define EXP2F(x) exp2f(x)
#endif

// ---------------- dtype detector: bf16 data -> even u16s have sane exponents (~100%);
// fp32 data read as u16 -> even u16s are low mantissa bits, ~28% sane. flag: 1 = fp32.
__global__ __launch_bounds__(256) void detect_dtype(const u16* __restrict__ x, unsigned* __restrict__ flag){
  __shared__ int cnt;
  if (threadIdx.x == 0) cnt = 0;
  __syncthreads();
  int sane = 0;
  for (int i = threadIdx.x; i < 4096; i += 256){
    unsigned e = (x[2 * i] >> 7) & 0xFFu;
    sane += (e >= 90u && e <= 160u) ? 1 : 0;
  }
  atomicAdd(&cnt, sane);
  __syncthreads();
  if (threadIdx.x == 0) *flag = (cnt < 2458) ? 1u : 0u;
}

// ---------------- transpose + pad: xT[b][j][ci] = x[b][ci][j-1] (bf16), rows 0 & 2049 zeroed by memset
__global__ __launch_bounds__(256) void transpose_pad(const void* __restrict__ xv, const unsigned* __restrict__ flagp,
                                                     u16* __restrict__ xT){
  int b = blockIdx.z, ci0 = blockIdx.y * 64, l0 = blockIdx.x * 64;
  __shared__ u16 tb[64 * 72];             // [l][ci], stride 72 pad
  const unsigned isf32 = *flagp;
  int t = threadIdx.x;
  int row = t >> 3, seg = t & 7;
  if (isf32){
    const float* xf = (const float*)xv;
    #pragma unroll
    for (int rnd = 0; rnd < 2; rnd++){
      int ci = row + rnd * 32;
      size_t off = ((size_t)(b * Cc + ci0 + ci)) * Ll + l0 + seg * 8;
      v4f a = *(const v4f*)(xf + off);
      v4f c4 = *(const v4f*)(xf + off + 4);
      #pragma unroll
      for (int j = 0; j < 4; j++) tb[(seg * 8 + j) * 72 + ci] = f2bf(a[j]);
      #pragma unroll
      for (int j = 0; j < 4; j++) tb[(seg * 8 + 4 + j) * 72 + ci] = f2bf(c4[j]);
    }
  } else {
    const u16* x = (const u16*)xv;
    #pragma unroll
    for (int rnd = 0; rnd < 2; rnd++){
      int ci = row + rnd * 32;
      u16x8 v = *(const u16x8*)(x + ((size_t)(b * Cc + ci0 + ci)) * Ll + l0 + seg * 8);
      #pragma unroll
      for (int j = 0; j < 8; j++) tb[(seg * 8 + j) * 72 + ci] = v[j];
    }
  }
  __syncthreads();
  #pragma unroll
  for (int rnd = 0; rnd < 2; rnd++){
    int l = row + rnd * 32;
    u16x8 v = *(const u16x8*)&tb[l * 72 + seg * 8];
    *(u16x8*)(xT + ((size_t)b * 2050 + 1 + l0 + l) * Cc + ci0 + seg * 8) = v;
  }
}

// ---------------- weight repack: wp[((conv*3+k)*512+co)*512+ci] = w_conv[co][ci][k] (bf16)
__global__ __launch_bounds__(256) void pack_w(const void* __restrict__ w0, const void* __restrict__ w1,
                                              const void* __restrict__ w2, const unsigned* __restrict__ flagp,
                                              u16* __restrict__ wp){
  int g = blockIdx.x * 256 + threadIdx.x;
  int ci = g & 511, co = (g >> 9) & 511, kc = g >> 18;   // kc = conv*3+k, 0..8
  int conv = kc / 3, k = kc - conv * 3;
  const void* w = (conv == 0) ? w0 : ((conv == 1) ? w1 : w2);
  size_t idx = (size_t)co * 1536 + ci * 3 + k;
  if (*flagp) wp[g] = f2bf(((const float*)w)[idx]);
  else        wp[g] = ((const u16*)w)[idx];
}

// ---------------- bias repack to bf16: bb[conv*512 + c]
__global__ __launch_bounds__(256) void pack_b(const void* __restrict__ b0, const void* __restrict__ b1,
                                              const void* __restrict__ b2, const unsigned* __restrict__ flagp,
                                              u16* __restrict__ bb){
  int g = blockIdx.x * 256 + threadIdx.x;
  if (g >= 1536) return;
  int conv = g >> 9, c = g & 511;
  const void* bsrc = (conv == 0) ? b0 : ((conv == 1) ? b1 : b2);
  if (*flagp) bb[g] = f2bf(((const float*)bsrc)[c]);
  else        bb[g] = ((const u16*)bsrc)[c];
}

// ---------------- conv as GEMM (m97 structure). MODE 0=q,1=k (M=co,N=l), 2=v (M=l,N=co).
template<int MODE>
__global__ __launch_bounds__(256) void conv_gemm(const u16* __restrict__ wp, const u16* __restrict__ xT,
                                                 const u16* __restrict__ bias, u16* __restrict__ outp){
  int b = blockIdx.y, bx = blockIdx.x;
  int mt, nt;
  if (MODE < 2){ mt = bx >> 4; nt = bx & 15; } else { mt = bx & 15; nt = bx >> 4; }
  int m0 = mt * 128, n0 = nt * 128;
  __shared__ u16 lA[128 * 32];
  __shared__ u16 lB[128 * 32];
  int t = threadIdx.x, wave = t >> 6, lane = t & 63, quad = lane >> 4, lid = lane & 15;
  int wm = (wave >> 1) * 64, wn = (wave & 1) * 64;
  v4f acc[4][4] = {};
  const size_t xbase = (size_t)b * 2050 * Cc;
  int srow = t >> 2, sseg = t & 3;

  for (int kc = 0; kc < 48; kc++){
    int kshift = kc >> 4, ci0 = (kc & 15) << 5;
    #pragma unroll
    for (int rnd = 0; rnd < 2; rnd++){
      int rr = srow + rnd * 64;
      const u16 *ga, *gb;
      if (MODE < 2){
        ga = wp + ((size_t)((MODE * 3 + kshift) * 512 + m0 + rr)) * 512 + ci0 + sseg * 8;
        gb = xT + xbase + ((size_t)(n0 + kshift + rr)) * 512 + ci0 + sseg * 8;
      } else {
        ga = xT + xbase + ((size_t)(m0 + kshift + rr)) * 512 + ci0 + sseg * 8;
        gb = wp + ((size_t)((6 + kshift) * 512 + n0 + rr)) * 512 + ci0 + sseg * 8;
      }
      async_cp16(ga, &lA[rnd * 2048 + t * 8]);
      async_cp16(gb, &lB[rnd * 2048 + t * 8]);
    }
    __syncthreads();
    v8s aF[4], bF[4];
    #pragma unroll
    for (int i = 0; i < 4; i++) aF[i] = *(const v8s*)&lA[(wm + i * 16 + lid) * 32 + quad * 8];
    #pragma unroll
    for (int i = 0; i < 4; i++) bF[i] = *(const v8s*)&lB[(wn + i * 16 + lid) * 32 + quad * 8];
    #pragma unroll
    for (int i = 0; i < 4; i++)
      #pragma unroll
      for (int j = 0; j < 4; j++)
        acc[i][j] = __builtin_amdgcn_mfma_f32_16x16x32_bf16(aF[i], bF[j], acc[i][j], 0, 0, 0);
    __syncthreads();
  }

  if (MODE < 2){
    const float qsc = (float)(1.4426950408889634 / 22.627416997969522);
    #pragma unroll
    for (int i = 0; i < 4; i++){
      int co = m0 + wm + i * 16 + quad * 4;
      float bv[4];
      #pragma unroll
      for (int r = 0; r < 4; r++) bv[r] = bf2f(bias[co + r]);
      #pragma unroll
      for (int j = 0; j < 4; j++){
        int l = n0 + wn + j * 16 + lid;
        u16x4 pk;
        #pragma unroll
        for (int r = 0; r < 4; r++){
          float v = acc[i][j][r] + bv[r];
          if (MODE == 0) v *= qsc;
          pk[r] = f2bf(v);
        }
        *(u16x4*)(outp + ((((size_t)b * Hh + (co >> 6)) * Ll + l) << 6) + (co & 63)) = pk;
      }
    }
  } else {
    #pragma unroll
    for (int i = 0; i < 4; i++){
      int l = m0 + wm + i * 16 + quad * 4;
      #pragma unroll
      for (int j = 0; j < 4; j++){
        int co = n0 + wn + j * 16 + lid;
        float bv = bf2f(bias[co]);
        u16x4 pk;
        #pragma unroll
        for (int r = 0; r < 4; r++) pk[r] = f2bf(acc[i][j][r] + bv);
        *(u16x4*)(outp + (((size_t)b * Cc + co) << 11) + l) = pk;
      }
    }
  }
}

// ---------------- flash attention. Block = (b, h, 128 q-rows). S^T = K·Q^T.
__global__ __launch_bounds__(256) void attn_kernel(const u16* __restrict__ qT, const u16* __restrict__ kT,
                                                   const u16* __restrict__ vN, const unsigned* __restrict__ flagp,
                                                   void* __restrict__ outv){
  int b = blockIdx.z, h = blockIdx.y, l0 = blockIdx.x * 128;
  int t = threadIdx.x, w = t >> 6, lane = t & 63, quad = lane >> 4, lid = lane & 15;
  __shared__ u16 kls[128 * 72];    // K tile [m][d], stride 72
  __shared__ u16 vls[64 * 136];    // V tile [d][m], stride 136
  __shared__ u16 pls[128 * 136];   // P tile [l][m], stride 136
  __shared__ float al[128];        // per-l alpha / 1/lsum
  const unsigned isf32 = *flagp;
  const size_t bh = (size_t)b * Hh + h;

  v8s qF[2][2];
  #pragma unroll
  for (int ci = 0; ci < 2; ci++)
    #pragma unroll
    for (int ks = 0; ks < 2; ks++)
      qF[ci][ks] = *(const v8s*)(qT + ((bh * Ll) + l0 + w * 32 + ci * 16 + lid) * 64 + ks * 32 + quad * 8);

  v4f o[2][4] = {};
  float mrun[2] = {-1e30f, -1e30f};
  float lrun[2] = {0.f, 0.f};

  for (int mt = 0; mt < 16; mt++){
    int m0 = mt * 128;
    {
      int row = t >> 3, seg = t & 7;
      #pragma unroll
      for (int rnd = 0; rnd < 4; rnd++){
        int m = row + rnd * 32;
        u16x8 v = *(const u16x8*)(kT + (bh * Ll + m0 + m) * 64 + seg * 8);
        *(u16x8*)&kls[m * 72 + seg * 8] = v;
      }
      int vrow = t >> 4, vseg = t & 15;
      #pragma unroll
      for (int rnd = 0; rnd < 4; rnd++){
        int d = vrow + rnd * 16;
        u16x8 v = *(const u16x8*)(vN + ((size_t)(b * Cc + h * Dh + d)) * Ll + m0 + vseg * 8);
        *(u16x8*)&vls[d * 136 + vseg * 8] = v;
      }
    }
    __syncthreads();

    v4f s[8][2] = {};
    #pragma unroll
    for (int ks = 0; ks < 2; ks++){
      v8s aF[8];
      #pragma unroll
      for (int mf = 0; mf < 8; mf++)
        aF[mf] = *(const v8s*)&kls[(mf * 16 + lid) * 72 + ks * 32 + quad * 8];
      #pragma unroll
      for (int mf = 0; mf < 8; mf++){
        s[mf][0] = __builtin_amdgcn_mfma_f32_16x16x32_bf16(aF[mf], qF[0][ks], s[mf][0], 0, 0, 0);
        s[mf][1] = __builtin_amdgcn_mfma_f32_16x16x32_bf16(aF[mf], qF[1][ks], s[mf][1], 0, 0, 0);
      }
    }

    float alv[2];
    #pragma unroll
    for (int ci = 0; ci < 2; ci++){
      float mx = -1e30f;
      #pragma unroll
      for (int mf = 0; mf < 8; mf++)
        #pragma unroll
        for (int r = 0; r < 4; r++) mx = fmaxf(mx, s[mf][ci][r]);
      mx = fmaxf(mx, __shfl_xor(mx, 16));
      mx = fmaxf(mx, __shfl_xor(mx, 32));
      float mnew = fmaxf(mrun[ci], mx);
      alv[ci] = EXP2F(mrun[ci] - mnew);
      mrun[ci] = mnew;
      float sm = 0.f;
      #pragma unroll
      for (int mf = 0; mf < 8; mf++)
        #pragma unroll
        for (int r = 0; r < 4; r++){
          float p = EXP2F(s[mf][ci][r] - mnew);
          s[mf][ci][r] = p;
          sm += p;
        }
      sm += __shfl_xor(sm, 16);
      sm += __shfl_xor(sm, 32);
      lrun[ci] = lrun[ci] * alv[ci] + sm;
    }
    if (quad == 0){
      al[w * 32 + lid] = alv[0];
      al[w * 32 + 16 + lid] = alv[1];
    }
    #pragma unroll
    for (int ci = 0; ci < 2; ci++)
      #pragma unroll
      for (int mf = 0; mf < 8; mf++){
        u16x4 pk;
        #pragma unroll
        for (int r = 0; r < 4; r++) pk[r] = f2bf(s[mf][ci][r]);
        *(u16x4*)&pls[(w * 32 + ci * 16 + lid) * 136 + mf * 16 + quad * 4] = pk;
      }
    __syncthreads();

    #pragma unroll
    for (int lf = 0; lf < 2; lf++){
      v4f av = *(const v4f*)&al[w * 32 + lf * 16 + quad * 4];
      #pragma unroll
      for (int df = 0; df < 4; df++) o[lf][df] *= av;
    }
    #pragma unroll
    for (int ks = 0; ks < 4; ks++){
      v8s aP[2], bV[4];
      #pragma unroll
      for (int lf = 0; lf < 2; lf++)
        aP[lf] = *(const v8s*)&pls[(w * 32 + lf * 16 + lid) * 136 + ks * 32 + quad * 8];
      #pragma unroll
      for (int df = 0; df < 4; df++)
        bV[df] = *(const v8s*)&vls[(df * 16 + lid) * 136 + ks * 32 + quad * 8];
      #pragma unroll
      for (int lf = 0; lf < 2; lf++)
        #pragma unroll
        for (int df = 0; df < 4; df++)
          o[lf][df] = __builtin_amdgcn_mfma_f32_16x16x32_bf16(aP[lf], bV[df], o[lf][df], 0, 0, 0);
    }
    __syncthreads();
  }

  if (quad == 0){
    al[w * 32 + lid] = 1.f / lrun[0];
    al[w * 32 + 16 + lid] = 1.f / lrun[1];
  }
  __syncthreads();
  #pragma unroll
  for (int lf = 0; lf < 2; lf++){
    v4f nv = *(const v4f*)&al[w * 32 + lf * 16 + quad * 4];
    #pragma unroll
    for (int df = 0; df < 4; df++){
      int d = df * 16 + lid;
      int l = l0 + w * 32 + lf * 16 + quad * 4;
      size_t ofs = (((bh << 6) + d) << 11) + l;
      if (isf32){
        v4f st;
        #pragma unroll
        for (int r = 0; r < 4; r++) st[r] = o[lf][df][r] * nv[r];
        *(v4f*)((float*)outv + ofs) = st;
      } else {
        u16x4 pk;
        #pragma unroll
        for (int r = 0; r < 4; r++) pk[r] = f2bf(o[lf][df][r] * nv[r]);
        *(u16x4*)((u16*)outv + ofs) = pk;
      }
    }
  }
}

extern "C" void kernel_launch(void* const* d_in, const int* in_sizes, int n_in,
                              void* d_out, int out_size, void* d_ws, size_t ws_size,
                              hipStream_t stream){
  const void* x  = d_in[0];
  const void* w0 = d_in[1];
  const void* b0 = d_in[2];
  const void* w1 = d_in[3];
  const void* b1 = d_in[4];
  const void* w2 = d_in[5];
  const void* b2 = d_in[6];
  u16* ws = (u16*)d_ws;
  unsigned* flag = (unsigned*)ws;                // 1 u32 at base (64 u16 slot, aligned)
  u16* xT = ws + 64;                             // [8][2050][512]  = 8,396,800 elems
  u16* wp = xT + (size_t)8 * 2050 * 512;         // [9][512][512]   = 2,359,296
  u16* bb = wp + (size_t)9 * 512 * 512;          // [3][512]        = 1,536
  u16* qT = bb + 1536;                           // [8][8][2048][64]= 8,388,608
  u16* kT = qT + (size_t)8 * 8 * 2048 * 64;
  u16* vN = kT + (size_t)8 * 8 * 2048 * 64;      // [8][512][2048]

  detect_dtype<<<1, 256, 0, stream>>>((const u16*)x, flag);
  (void)hipMemsetAsync(xT, 0, (size_t)8 * 2050 * 512 * 2, stream);  // zero pad rows
  transpose_pad<<<dim3(32, 8, 8), 256, 0, stream>>>(x, flag, xT);
  pack_w<<<dim3(9 * 512 * 512 / 256), 256, 0, stream>>>(w0, w1, w2, flag, wp);
  pack_b<<<dim3(6), 256, 0, stream>>>(b0, b1, b2, flag, bb);
  conv_gemm<0><<<dim3(64, 8), 256, 0, stream>>>(wp, xT, bb, qT);
  conv_gemm<1><<<dim3(64, 8), 256, 0, stream>>>(wp, xT, bb + 512, kT);
  conv_gemm<2><<<dim3(64, 8), 256, 0, stream>>>(wp, xT, bb + 1024, vN);
  attn_kernel<<<dim3(16, 8, 8), 256, 0, stream>>>(qT, kT, vN, flag, d_out);
}